// Round 1
// baseline (2776.878 us; speedup 1.0000x reference)
//
#include <hip/hip_runtime.h>
#include <hip/hip_bf16.h>

#define NBLK 64
#define BS   128
#define GSZ  8192   // NBLK * BS

// ---------------------------------------------------------------------------
// Kernel 1: P = sinkhorn(softmax(clamp(w*scale,-1,1)/3)) per 128x128 block.
// One workgroup (128 threads) per block; whole block lives in LDS.
// [BS][BS+1] padding -> conflict-free for both row-owner and col-owner passes.
// ---------------------------------------------------------------------------
__global__ __launch_bounds__(128) void k_sinkhorn(const float* __restrict__ w,
                                                  const float* __restrict__ scale_p,
                                                  float* __restrict__ P) {
    __shared__ float M[BS][BS + 1];
    const int b = blockIdx.x;
    const int t = threadIdx.x;
    const float scale = *scale_p;

    // coalesced load; straight-through clamp then /tau (tau = 3.0)
    for (int r = 0; r < BS; ++r) {
        float x = w[((size_t)b * BS + r) * BS + t] * scale;
        x = fminf(fmaxf(x, -1.0f), 1.0f);
        M[r][t] = x / 3.0f;
    }
    __syncthreads();

    // softmax along rows (thread t owns row t) — matches jax.nn.softmax
    {
        float mx = M[t][0];
        for (int c = 1; c < BS; ++c) mx = fmaxf(mx, M[t][c]);
        float s = 0.0f;
        for (int c = 0; c < BS; ++c) { float e = expf(M[t][c] - mx); M[t][c] = e; s += e; }
        for (int c = 0; c < BS; ++c) M[t][c] /= s;
    }
    __syncthreads();

    // 5 sinkhorn iterations: row-normalize then col-normalize
    for (int it = 0; it < 5; ++it) {
        {
            float s = 0.0f;
            for (int c = 0; c < BS; ++c) s += M[t][c];
            for (int c = 0; c < BS; ++c) M[t][c] /= s;
        }
        __syncthreads();
        {
            float s = 0.0f;
            for (int r = 0; r < BS; ++r) s += M[r][t];
            for (int r = 0; r < BS; ++r) M[r][t] /= s;
        }
        __syncthreads();
    }

    for (int r = 0; r < BS; ++r)
        P[((size_t)b * BS + r) * BS + t] = M[r][t];
}

// ---------------------------------------------------------------------------
// Kernel 2: exact Jonker-Volgenant LAP (e-maxx variant, matches reference's
// _lsa_min incl. np.argmin first-min tie-break) on cost = -P, float64 duals.
// One wave (64 lanes) per block; lane owns columns lane+1 and lane+65.
// minv/v/used in registers; u/p/way in volatile LDS (single-wave lockstep).
// ---------------------------------------------------------------------------
__global__ __launch_bounds__(64) void k_hungarian(const float* __restrict__ P,
                                                  int* __restrict__ colof) {
    __shared__ float  C[BS][BS];
    __shared__ double u_s[BS + 1];
    __shared__ int    p_s[BS + 1];
    __shared__ int    way_s[BS + 1];
    volatile double* u   = u_s;
    volatile int*    p   = p_s;
    volatile int*    way = way_s;

    const int b    = blockIdx.x;
    const int lane = threadIdx.x;   // 0..63

    for (int k = lane; k < BS * BS; k += 64)
        (&C[0][0])[k] = P[(size_t)b * BS * BS + k];
    for (int j = lane; j <= BS; j += 64) { u[j] = 0.0; p[j] = 0; way[j] = 0; }
    __syncthreads();

    const int jA = lane + 1;
    const int jB = lane + 65;
    double vA = 0.0, vB = 0.0;

    for (int i = 1; i <= BS; ++i) {
        if (lane == 0) p[0] = i;
        int j0 = 0;
        double minvA = 1e18, minvB = 1e18;
        bool usedA = false, usedB = false;
        int rowA = 0, rowB = 0;

        while (true) {
            const int i0 = (j0 == 0) ? i : p[j0];     // LDS broadcast read
            if (j0 == jA) { usedA = true; rowA = i0; }
            if (j0 == jB) { usedB = true; rowB = i0; }
            const double ui0 = u[i0];

            if (!usedA) {
                double cur = -(double)C[i0 - 1][jA - 1] - ui0 - vA;
                if (cur < minvA) { minvA = cur; way[jA] = j0; }
            }
            if (!usedB) {
                double cur = -(double)C[i0 - 1][jB - 1] - ui0 - vB;
                if (cur < minvB) { minvB = cur; way[jB] = j0; }
            }

            // lane-local (value, index) lex-min; jA<jB so tie keeps smaller j
            double mval = usedA ? 1e18 : minvA;
            int    midx = jA;
            if (!usedB && minvB < mval) { mval = minvB; midx = jB; }

            // wave argmin, first-index tie-break (== np.argmin semantics)
            for (int off = 32; off; off >>= 1) {
                double ov = __shfl_xor(mval, off);
                int    oj = __shfl_xor(midx, off);
                if (ov < mval || (ov == mval && oj < midx)) { mval = ov; midx = oj; }
            }
            const double delta = mval;
            const int    j1    = midx;

            // dual updates: u[p[j]] += delta for all used j (col 0 -> u[i]),
            // v[used] -= delta, minv[free] -= delta
            if (lane == 0) u[i] = u[i] + delta;
            if (usedA) { u[rowA] = u[rowA] + delta; vA -= delta; } else { minvA -= delta; }
            if (usedB) { u[rowB] = u[rowB] + delta; vB -= delta; } else { minvB -= delta; }

            j0 = j1;
            if (p[j0] == 0) break;                    // reached a free column
        }

        // augment along alternating path (serial, lane 0)
        if (lane == 0) {
            int j = j0;
            while (j != 0) { int jn = way[j]; p[j] = p[jn]; j = jn; }
        }
    }

    // p[j] = row (1-based) assigned to column j
    {
        int rA = p[jA]; colof[b * BS + (rA - 1)] = jA - 1;
        int rB = p[jB]; colof[b * BS + (rB - 1)] = jB - 1;
    }
}

// ---------------------------------------------------------------------------
// Kernel 3: zero-fill the 8192x8192 f32 output (float4 grid-stride).
// ---------------------------------------------------------------------------
__global__ __launch_bounds__(256) void k_zero(float4* __restrict__ out, int n4) {
    int idx    = blockIdx.x * blockDim.x + threadIdx.x;
    int stride = gridDim.x * blockDim.x;
    const float4 z = make_float4(0.f, 0.f, 0.f, 0.f);
    for (int k = idx; k < n4; k += stride) out[k] = z;
}

// ---------------------------------------------------------------------------
// Kernel 4: scatter the 8192 ones: out[r, b*128 + colof[r]] = 1.
// ---------------------------------------------------------------------------
__global__ __launch_bounds__(256) void k_ones(const int* __restrict__ colof,
                                              float* __restrict__ out) {
    int r = blockIdx.x * blockDim.x + threadIdx.x;
    if (r < GSZ) {
        int b = r / BS;
        int c = colof[r];
        out[(size_t)r * GSZ + (size_t)(b * BS + c)] = 1.0f;
    }
}

extern "C" void kernel_launch(void* const* d_in, const int* in_sizes, int n_in,
                              void* d_out, int out_size, void* d_ws, size_t ws_size,
                              hipStream_t stream) {
    const float* w     = (const float*)d_in[0];
    const float* scale = (const float*)d_in[1];
    float* out = (float*)d_out;

    float* P     = (float*)d_ws;                                          // 4 MB
    int*   colof = (int*)((char*)d_ws + (size_t)NBLK * BS * BS * sizeof(float)); // 32 KB

    k_sinkhorn<<<NBLK, BS, 0, stream>>>(w, scale, P);
    k_hungarian<<<NBLK, 64, 0, stream>>>(P, colof);
    k_zero<<<2048, 256, 0, stream>>>((float4*)out, (GSZ * GSZ) / 4);
    k_ones<<<(GSZ + 255) / 256, 256, 0, stream>>>(colof, out);
}

// Round 3
// 1034.234 us; speedup vs baseline: 2.6850x; 2.6850x over previous
//
#include <hip/hip_runtime.h>
#include <hip/hip_bf16.h>

#define NBLK 64
#define BS   128
#define GSZ  8192   // NBLK * BS

// ---------- wave-uniform register fetch helpers (lane index must be uniform) ----------
__device__ __forceinline__ int rl32(int v, int sl) {
    return __builtin_amdgcn_readlane(v, sl);
}
__device__ __forceinline__ double rl64(double v, int sl) {
    union { double d; unsigned u[2]; } a; a.d = v;
    unsigned lo = (unsigned)__builtin_amdgcn_readlane((int)a.u[0], sl);
    unsigned hi = (unsigned)__builtin_amdgcn_readlane((int)a.u[1], sl);
    union { unsigned u[2]; double d; } r; r.u[0] = lo; r.u[1] = hi;
    return r.d;
}
__device__ __forceinline__ unsigned long long rlu64(unsigned long long v, int sl) {
    unsigned lo = (unsigned)__builtin_amdgcn_readlane((int)(unsigned)(v & 0xffffffffull), sl);
    unsigned hi = (unsigned)__builtin_amdgcn_readlane((int)(unsigned)(v >> 32), sl);
    return ((unsigned long long)hi << 32) | lo;
}
// monotone f64 -> u64 key; low 8 bits replaced by column (1..128) for
// np.argmin-style smallest-index tie-break. 8-bit mantissa truncation only
// merges values within 2^-45 relative — exact ties stay exact.
__device__ __forceinline__ unsigned long long pkey(double m, int col) {
    union { double d; unsigned long long u; } a; a.d = m;
    unsigned long long x = a.u;
    x = (x >> 63) ? ~x : (x | 0x8000000000000000ull);
    return (x & ~0xFFull) | (unsigned long long)(unsigned)col;
}

// ---------------------------------------------------------------------------
// Fused kernel: sinkhorn (128 thr) -> { wave0: seeded register-JV LAP,
// wave1: zero-fill the block's 128x8192 output stripe } -> scatter ones.
// ---------------------------------------------------------------------------
__global__ __launch_bounds__(128) void k_fused(const float* __restrict__ w,
                                               const float* __restrict__ scale_p,
                                               float* __restrict__ out) {
    __shared__ float M[BS][BS + 1];   // [128][129] f32: conflict-free rows+cols
    __shared__ int   rowasg[BS];
    float* Mf = &M[0][0];

    const int b = blockIdx.x;
    const int t = threadIdx.x;
    const float scale = *scale_p;

    // ---- sinkhorn: P = sinkhorn(softmax(clamp(w*scale,-1,1)/3)) ----
    for (int r = 0; r < BS; ++r) {
        float x = w[((size_t)b * BS + r) * BS + t] * scale;
        x = fminf(fmaxf(x, -1.0f), 1.0f);
        M[r][t] = x / 3.0f;
    }
    __syncthreads();
    {   // softmax along rows (thread t owns row t)
        float mx = M[t][0];
        for (int c = 1; c < BS; ++c) mx = fmaxf(mx, M[t][c]);
        float s = 0.0f;
        for (int c = 0; c < BS; ++c) { float e = expf(M[t][c] - mx); M[t][c] = e; s += e; }
        float rs = 1.0f / s;
        for (int c = 0; c < BS; ++c) M[t][c] *= rs;
    }
    __syncthreads();
    for (int it = 0; it < 5; ++it) {
        {   float s = 0.0f;
            for (int c = 0; c < BS; ++c) s += M[t][c];
            float rs = 1.0f / s;
            for (int c = 0; c < BS; ++c) M[t][c] *= rs;
        }
        __syncthreads();
        {   float s = 0.0f;
            for (int r = 0; r < BS; ++r) s += M[r][t];
            float rs = 1.0f / s;
            for (int r = 0; r < BS; ++r) M[r][t] *= rs;
        }
        __syncthreads();
    }

    int pA = 0, pB = 0;   // row (1-based) assigned to cols t+1 / t+65; 0 = free

    if (t >= 64) {
        // ---- wave1: zero the 128-row output stripe (hidden under wave0's LAP)
        const int l = t - 64;
        float4 z = make_float4(0.f, 0.f, 0.f, 0.f);
        float4* o4 = reinterpret_cast<float4*>(out + (size_t)b * BS * GSZ);
        for (int k = l; k < BS * GSZ / 4; k += 64) o4[k] = z;
    } else {
        // ---- wave0: exact LAP on cost = -P, all state in registers ----
        const int jAcol = t + 1, jBcol = t + 65;
        double uA = 0.0, uB = 0.0, vA, vB;

        // column reduction seed: v[j] = min_i cost = -(max_i P); greedy assign
        {
            float cmA = Mf[t];      int raA = 0;
            float cmB = Mf[t + 64]; int raB = 0;
            for (int r = 1; r < BS; ++r) {
                float xA = Mf[r * (BS + 1) + t];
                if (xA > cmA) { cmA = xA; raA = r; }
                float xB = Mf[r * (BS + 1) + t + 64];
                if (xB > cmB) { cmB = xB; raB = r; }
            }
            vA = -(double)cmA; vB = -(double)cmB;
            rowasg[t] = 0x7FFFFFFF; rowasg[t + 64] = 0x7FFFFFFF;
            __threadfence_block();
            atomicMin(&rowasg[raA], jAcol);
            atomicMin(&rowasg[raB], jBcol);
            __threadfence_block();
            pA = (rowasg[raA] == jAcol) ? raA + 1 : 0;
            pB = (rowasg[raB] == jBcol) ? raB + 1 : 0;
        }

        // unassigned-row masks (rows 1..64 in un0, 65..128 in un1)
        unsigned long long un0 = __ballot(rowasg[t]      == 0x7FFFFFFF);
        unsigned long long un1 = __ballot(rowasg[t + 64] == 0x7FFFFFFF);

        while (un0 | un1) {
            int i;
            if (un0) { int r = __builtin_ctzll(un0); un0 &= un0 - 1; i = r + 1; }
            else     { int r = __builtin_ctzll(un1); un1 &= un1 - 1; i = r + 65; }

            bool usedA = false, usedB = false;
            double mA = 1e18, mB = 1e18, SUM = 0.0;   // stored m = true_minv + SUM
            unsigned long long keyA = ~0ull, keyB = ~0ull;
            int wayA = 0, wayB = 0;
            int i0 = i, j0 = 0;
            double ui0 = 0.0;

            for (int guard = 0; guard <= BS + 2; ++guard) {
                // scan row i0 against this lane's two columns
                float cA = Mf[(i0 - 1) * (BS + 1) + t];
                float cB = Mf[(i0 - 1) * (BS + 1) + t + 64];
                if (!usedA) {
                    double nd = (-(double)cA - ui0 - vA) + SUM;
                    if (nd < mA) { mA = nd; wayA = j0; keyA = pkey(nd, jAcol); }
                }
                if (!usedB) {
                    double nd = (-(double)cB - ui0 - vB) + SUM;
                    if (nd < mB) { mB = nd; wayB = j0; keyB = pkey(nd, jBcol); }
                }
                // 5-level u64 butterfly + scalar finish -> global argmin
                unsigned long long k = keyA < keyB ? keyA : keyB;
                #pragma unroll
                for (int off = 1; off < 32; off <<= 1) {
                    unsigned long long o = __shfl_xor(k, off);
                    if (o < k) k = o;
                }
                unsigned long long kw0 = rlu64(k, 0), kw1 = rlu64(k, 32);
                unsigned long long kw = kw0 < kw1 ? kw0 : kw1;
                const int  j1 = (int)(kw & 0xFFull);
                const int  sl = (j1 - 1) & 63;
                const bool hb = j1 > 64;

                double m_win = rl64(hb ? mB : mA, sl);   // exact f64 min value
                double delta = m_win - SUM;
                SUM += delta;
                if (usedA) { uA += delta; vA -= delta; }
                if (usedB) { uB += delta; vB -= delta; }

                int pj = rl32(hb ? pB : pA, sl);
                j0 = j1;
                if (pj == 0) break;                      // free column: augment
                ui0 = rl64(hb ? uB : uA, sl);            // owner still unmarked
                i0 = pj;
                if (!hb && t == sl) { usedA = true; keyA = ~0ull; }
                if ( hb && t == sl) { usedB = true; keyB = ~0ull; }
            }

            // augment along way-chain; duals u travel with their rows
            int jc = j0;
            for (int guard = 0; guard <= BS + 2; ++guard) {
                const int  slc = (jc - 1) & 63;
                const bool hc  = jc > 64;
                int jp = rl32(hc ? wayB : wayA, slc);
                int nprow; double nu;
                if (jp == 0) { nprow = i; nu = SUM; }    // u[i] accumulated = SUM
                else {
                    const int  slp = (jp - 1) & 63;
                    const bool hp  = jp > 64;
                    nprow = rl32(hp ? pB : pA, slp);
                    nu    = rl64(hp ? uB : uA, slp);
                }
                if (!hc) { if (t == slc) { pA = nprow; uA = nu; } }
                else     { if (t == slc) { pB = nprow; uB = nu; } }
                if (jp == 0) break;
                jc = jp;
            }
        }
    }

    __syncthreads();   // stripe fully zeroed, assignment final

    if (t < 64) {
        const size_t base = (size_t)b * BS;
        if (pA >= 1) out[(base + (size_t)(pA - 1)) * GSZ + base + t]      = 1.0f;
        if (pB >= 1) out[(base + (size_t)(pB - 1)) * GSZ + base + t + 64] = 1.0f;
    }
}

extern "C" void kernel_launch(void* const* d_in, const int* in_sizes, int n_in,
                              void* d_out, int out_size, void* d_ws, size_t ws_size,
                              hipStream_t stream) {
    const float* w     = (const float*)d_in[0];
    const float* scale = (const float*)d_in[1];
    float* out = (float*)d_out;
    k_fused<<<NBLK, BS, 0, stream>>>(w, scale, out);
}

// Round 4
// 780.296 us; speedup vs baseline: 3.5587x; 1.3254x over previous
//
#include <hip/hip_runtime.h>
#include <hip/hip_bf16.h>

#define NBLK 64
#define BS   128
#define GSZ  8192   // NBLK * BS

// ---------- wave-uniform register fetch helpers (lane index must be uniform) ----------
__device__ __forceinline__ int rl32(int v, int sl) {
    return __builtin_amdgcn_readlane(v, sl);
}
__device__ __forceinline__ double rl64(double v, int sl) {
    union { double d; unsigned u[2]; } a; a.d = v;
    unsigned lo = (unsigned)__builtin_amdgcn_readlane((int)a.u[0], sl);
    unsigned hi = (unsigned)__builtin_amdgcn_readlane((int)a.u[1], sl);
    union { unsigned u[2]; double d; } r; r.u[0] = lo; r.u[1] = hi;
    return r.d;
}
// monotone f64 -> u64 key; low 8 bits replaced by column (1..128) for
// np.argmin-style smallest-index tie-break. 8-bit mantissa truncation only
// merges values within 2^-45 relative — exact ties stay exact.
__device__ __forceinline__ unsigned long long pkey(double m, int col) {
    union { double d; unsigned long long u; } a; a.d = m;
    unsigned long long x = a.u;
    x = (x >> 63) ? ~x : (x | 0x8000000000000000ull);
    return (x & ~0xFFull) | (unsigned long long)(unsigned)col;
}

// rocPRIM-style wave64 min via DPP: row_shr 1/2/4/8 then row_bcast 15/31.
// bound_ctrl=false -> invalid-source lanes keep 'old' (= own x). Result in
// lane 63, returned uniform via readlane.
__device__ __forceinline__ unsigned wave_min_u32_dpp(unsigned x) {
    x = min(x, (unsigned)__builtin_amdgcn_update_dpp((int)x, (int)x, 0x111, 0xf, 0xf, false)); // row_shr:1
    x = min(x, (unsigned)__builtin_amdgcn_update_dpp((int)x, (int)x, 0x112, 0xf, 0xf, false)); // row_shr:2
    x = min(x, (unsigned)__builtin_amdgcn_update_dpp((int)x, (int)x, 0x114, 0xf, 0xf, false)); // row_shr:4
    x = min(x, (unsigned)__builtin_amdgcn_update_dpp((int)x, (int)x, 0x118, 0xf, 0xf, false)); // row_shr:8
    x = min(x, (unsigned)__builtin_amdgcn_update_dpp((int)x, (int)x, 0x142, 0xa, 0xf, false)); // row_bcast:15
    x = min(x, (unsigned)__builtin_amdgcn_update_dpp((int)x, (int)x, 0x143, 0xc, 0xf, false)); // row_bcast:31
    return (unsigned)__builtin_amdgcn_readlane((int)x, 63);
}

// exact u64-key min across the wave: hi32 DPP min + ballot; unique -> one
// dynamic readlane, else lo32 DPP min among hi-matching lanes.
__device__ __forceinline__ unsigned long long wave_min_key(unsigned long long k) {
    unsigned hi = (unsigned)(k >> 32);
    unsigned lo = (unsigned)k;
    unsigned mh = wave_min_u32_dpp(hi);
    unsigned long long msk = __ballot(hi == mh);
    unsigned lo_cand = (hi == mh) ? lo : 0xFFFFFFFFu;
    unsigned ml;
    if (__popcll(msk) == 1) {
        ml = (unsigned)__builtin_amdgcn_readlane((int)lo_cand, (int)__builtin_ctzll(msk));
    } else {
        ml = wave_min_u32_dpp(lo_cand);
    }
    return ((unsigned long long)mh << 32) | ml;
}

// ---------------------------------------------------------------------------
// Fused kernel (256 thr): sinkhorn (first 128 thr) -> { wave0: column-reduction
// + ARR + register-JV Dijkstra LAP, waves1-3: zero-fill the 128x8192 stripe }
// -> scatter ones.
// ---------------------------------------------------------------------------
__global__ __launch_bounds__(256) void k_fused(const float* __restrict__ w,
                                               const float* __restrict__ scale_p,
                                               float* __restrict__ out) {
    __shared__ float M[BS][BS + 1];   // [128][129] f32: conflict-free rows+cols
    __shared__ int   rowasg[BS];
    float* Mf = &M[0][0];

    const int b = blockIdx.x;
    const int t = threadIdx.x;
    const float scale = *scale_p;

    // ---- sinkhorn: P = sinkhorn(softmax(clamp(w*scale,-1,1)/3)) ----
    if (t < BS) {
        for (int r = 0; r < BS; ++r) {
            float x = w[((size_t)b * BS + r) * BS + t] * scale;
            x = fminf(fmaxf(x, -1.0f), 1.0f);
            M[r][t] = x / 3.0f;
        }
    }
    __syncthreads();
    if (t < BS) {   // softmax along rows (thread t owns row t)
        float mx = M[t][0];
        for (int c = 1; c < BS; ++c) mx = fmaxf(mx, M[t][c]);
        float s = 0.0f;
        for (int c = 0; c < BS; ++c) { float e = expf(M[t][c] - mx); M[t][c] = e; s += e; }
        float rs = 1.0f / s;
        for (int c = 0; c < BS; ++c) M[t][c] *= rs;
    }
    __syncthreads();
    for (int it = 0; it < 5; ++it) {
        if (t < BS) {
            float s = 0.0f;
            for (int c = 0; c < BS; ++c) s += M[t][c];
            float rs = 1.0f / s;
            for (int c = 0; c < BS; ++c) M[t][c] *= rs;
        }
        __syncthreads();
        if (t < BS) {
            float s = 0.0f;
            for (int r = 0; r < BS; ++r) s += M[r][t];
            float rs = 1.0f / s;
            for (int r = 0; r < BS; ++r) M[r][t] *= rs;
        }
        __syncthreads();
    }

    int pA = 0, pB = 0;   // row (1-based) assigned to cols t+1 / t+65; 0 = free

    if (t >= 64) {
        // ---- waves1-3: zero the 128-row output stripe (hidden under LAP) ----
        const int l = t - 64;   // 0..191
        float4 z = make_float4(0.f, 0.f, 0.f, 0.f);
        float4* o4 = reinterpret_cast<float4*>(out + (size_t)b * BS * GSZ);
        for (int k = l; k < BS * GSZ / 4; k += 192) o4[k] = z;
    } else {
        // ---- wave0: exact LAP on cost = -P, all state in registers ----
        const int jAcol = t + 1, jBcol = t + 65;
        double uA = 0.0, uB = 0.0, vA, vB;

        // column reduction seed: v[j] = min_i cost = -(max_i P); greedy assign
        {
            float cmA = Mf[t];      int raA = 0;
            float cmB = Mf[t + 64]; int raB = 0;
            for (int r = 1; r < BS; ++r) {
                float xA = Mf[r * (BS + 1) + t];
                if (xA > cmA) { cmA = xA; raA = r; }
                float xB = Mf[r * (BS + 1) + t + 64];
                if (xB > cmB) { cmB = xB; raB = r; }
            }
            vA = -(double)cmA; vB = -(double)cmB;
            rowasg[t] = 0x7FFFFFFF; rowasg[t + 64] = 0x7FFFFFFF;
            __threadfence_block();
            atomicMin(&rowasg[raA], jAcol);
            atomicMin(&rowasg[raB], jBcol);
            __threadfence_block();
            pA = (rowasg[raA] == jAcol) ? raA + 1 : 0;
            pB = (rowasg[raB] == jBcol) ? raB + 1 : 0;
        }

        // unassigned-row masks (rows 1..64 in un0, 65..128 in un1)
        unsigned long long un0 = __ballot(rowasg[t]      == 0x7FFFFFFF);
        unsigned long long un1 = __ballot(rowasg[t + 64] == 0x7FFFFFFF);

        // ---- ARR: augmenting row reduction (lapjv), capped; every step keeps
        // duals feasible (v only decreases; free rows use u=0) and assigned
        // pairs tight (u[i]=u2), so Dijkstra below stays exact from any state.
        for (int steps = 0; (un0 | un1) && steps < 512; ++steps) {
            int i;
            if (un0) i = __builtin_ctzll(un0) + 1;
            else     i = __builtin_ctzll(un1) + 65;

            double dA = -(double)Mf[(i - 1) * (BS + 1) + t]      - vA;
            double dB = -(double)Mf[(i - 1) * (BS + 1) + t + 64] - vB;
            unsigned long long kA = pkey(dA, jAcol), kB = pkey(dB, jBcol);

            unsigned long long k1 = wave_min_key(kA < kB ? kA : kB);
            const int  j1  = (int)(k1 & 0xFFull);
            const int  sl1 = (j1 - 1) & 63;
            const bool h1  = j1 > 64;
            double u1 = rl64(h1 ? dB : dA, sl1);

            unsigned long long kA2 = (jAcol == j1) ? ~0ull : kA;
            unsigned long long kB2 = (jBcol == j1) ? ~0ull : kB;
            unsigned long long k2 = wave_min_key(kA2 < kB2 ? kA2 : kB2);
            const int  j2  = (int)(k2 & 0xFFull);
            const int  sl2 = (j2 - 1) & 63;
            const bool h2  = j2 > 64;
            double u2 = rl64(h2 ? dB : dA, sl2);

            int i1 = rl32(h1 ? pB : pA, sl1);   // previous owner of j1 (0 = none)

            if (t == sl1) {
                if (h1) { pB = i; uB = u2; if (u1 < u2) vB -= (u2 - u1); }
                else    { pA = i; uA = u2; if (u1 < u2) vA -= (u2 - u1); }
            }
            if (i <= 64) un0 &= ~(1ull << (i - 1)); else un1 &= ~(1ull << (i - 65));
            if (i1 > 0) {
                if (i1 <= 64) un0 |= 1ull << (i1 - 1); else un1 |= 1ull << (i1 - 65);
            }
        }

        // ---- Dijkstra phases for remaining free rows (exact JV) ----
        while (un0 | un1) {
            int i;
            if (un0) { int r = __builtin_ctzll(un0); un0 &= un0 - 1; i = r + 1; }
            else     { int r = __builtin_ctzll(un1); un1 &= un1 - 1; i = r + 65; }

            bool usedA = false, usedB = false;
            double mA = 1e18, mB = 1e18, SUM = 0.0;   // stored m = true_minv + SUM
            unsigned long long keyA = ~0ull, keyB = ~0ull;
            int wayA = 0, wayB = 0;
            int i0 = i, j0 = 0;
            double ui0 = 0.0;

            for (int guard = 0; guard <= BS + 2; ++guard) {
                // scan row i0 against this lane's two columns
                float cA = Mf[(i0 - 1) * (BS + 1) + t];
                float cB = Mf[(i0 - 1) * (BS + 1) + t + 64];
                if (!usedA) {
                    double nd = (-(double)cA - ui0 - vA) + SUM;
                    if (nd < mA) { mA = nd; wayA = j0; keyA = pkey(nd, jAcol); }
                }
                if (!usedB) {
                    double nd = (-(double)cB - ui0 - vB) + SUM;
                    if (nd < mB) { mB = nd; wayB = j0; keyB = pkey(nd, jBcol); }
                }
                unsigned long long kw = wave_min_key(keyA < keyB ? keyA : keyB);
                const int  j1 = (int)(kw & 0xFFull);
                const int  sl = (j1 - 1) & 63;
                const bool hb = j1 > 64;

                double m_win = rl64(hb ? mB : mA, sl);   // exact f64 min value
                double delta = m_win - SUM;
                SUM += delta;
                if (usedA) { uA += delta; vA -= delta; }
                if (usedB) { uB += delta; vB -= delta; }

                int pj = rl32(hb ? pB : pA, sl);
                j0 = j1;
                if (pj == 0) break;                      // free column: augment
                ui0 = rl64(hb ? uB : uA, sl);            // owner still unmarked
                i0 = pj;
                if (!hb && t == sl) { usedA = true; keyA = ~0ull; }
                if ( hb && t == sl) { usedB = true; keyB = ~0ull; }
            }

            // augment along way-chain; duals u travel with their rows
            int jc = j0;
            for (int guard = 0; guard <= BS + 2; ++guard) {
                const int  slc = (jc - 1) & 63;
                const bool hc  = jc > 64;
                int jp = rl32(hc ? wayB : wayA, slc);
                int nprow; double nu;
                if (jp == 0) { nprow = i; nu = SUM; }    // start row: u was 0
                else {
                    const int  slp = (jp - 1) & 63;
                    const bool hp  = jp > 64;
                    nprow = rl32(hp ? pB : pA, slp);
                    nu    = rl64(hp ? uB : uA, slp);
                }
                if (!hc) { if (t == slc) { pA = nprow; uA = nu; } }
                else     { if (t == slc) { pB = nprow; uB = nu; } }
                if (jp == 0) break;
                jc = jp;
            }
        }
    }

    __syncthreads();   // stripe fully zeroed, assignment final

    if (t < 64) {
        const size_t base = (size_t)b * BS;
        if (pA >= 1) out[(base + (size_t)(pA - 1)) * GSZ + base + t]      = 1.0f;
        if (pB >= 1) out[(base + (size_t)(pB - 1)) * GSZ + base + t + 64] = 1.0f;
    }
}

extern "C" void kernel_launch(void* const* d_in, const int* in_sizes, int n_in,
                              void* d_out, int out_size, void* d_ws, size_t ws_size,
                              hipStream_t stream) {
    const float* w     = (const float*)d_in[0];
    const float* scale = (const float*)d_in[1];
    float* out = (float*)d_out;
    k_fused<<<NBLK, 256, 0, stream>>>(w, scale, out);
}